// Round 6
// baseline (239.967 us; speedup 1.0000x reference)
//
#include <hip/hip_runtime.h>
#include <math.h>

#define NN 50000
#define NE 800000
#define F 64
#define NCLS 16

#define BKS 7              // log2(nodes per bucket)
#define BKN 128            // nodes per bucket
#define NBK 391            // ceil(50000/128)
#define B1C 4096           // edges per bucket1 block
#define B1B 196            // ceil(NE/B1C)
#define CAP2 3072          // max edges per bucket

typedef unsigned short u16;
typedef __attribute__((ext_vector_type(4))) unsigned short ushort4v;

__device__ __forceinline__ float bf2f(u16 h) {
    return __uint_as_float((unsigned)h << 16);
}
__device__ __forceinline__ u16 f2bf(float f) {   // round-nearest-even
    unsigned u = __float_as_uint(f);
    return (u16)((u + 0x7fffu + ((u >> 16) & 1u)) >> 16);
}

__global__ void k_zeroi(int* __restrict__ p, int n) {
    int i = blockIdx.x * 256 + threadIdx.x;
    if (i < n) p[i] = 0;
}

// ---------------- pass 0: coarse bucket histogram ----------------

__global__ __launch_bounds__(256) void k_bkhist(const int* __restrict__ col,
                                                int* __restrict__ bkcnt) {
    __shared__ int h[NBK];
    for (int i = threadIdx.x; i < NBK; i += 256) h[i] = 0;
    __syncthreads();
    int stride = gridDim.x * 256;
    for (int e = blockIdx.x * 256 + threadIdx.x; e < NE; e += stride)
        atomicAdd(&h[col[e] >> BKS], 1);
    __syncthreads();
    for (int i = threadIdx.x; i < NBK; i += 256) {
        int v = h[i];
        if (v) atomicAdd(&bkcnt[i], v);
    }
}

// ---------------- scan bucket counts -> bases + cursors (1 block) ----------------

__global__ __launch_bounds__(512) void k_scan_bk(const int* __restrict__ bkcnt,
                                                 int* __restrict__ bkbase,
                                                 int* __restrict__ bkcur) {
    __shared__ int sa[512], sb[512];
    int t = threadIdx.x;
    int c = (t < NBK) ? bkcnt[t] : 0;
    sa[t] = c;
    __syncthreads();
    int* src = sa; int* dst = sb;
#pragma unroll
    for (int off = 1; off < 512; off <<= 1) {
        dst[t] = src[t] + ((t >= off) ? src[t - off] : 0);
        __syncthreads();
        int* tq = src; src = dst; dst = tq;
    }
    if (t < NBK) {
        int excl = src[t] - c;
        bkbase[t] = excl;
        bkcur[t]  = excl;
    }
    if (t == NBK) bkbase[t] = NE;
}

// ---------------- pass 1: group edges by bucket (LDS), flush contiguous runs ------

__global__ __launch_bounds__(512) void k_bucket1(const int* __restrict__ row,
                                                 const int* __restrict__ col,
                                                 const float* __restrict__ w,
                                                 int* __restrict__ bkcur,
                                                 int2* __restrict__ tmp) {
    __shared__ int hist[512];
    __shared__ int sa[512], sb[512];
    __shared__ int lbase[512];
    __shared__ int gbase[512];
    __shared__ int lcur[512];
    __shared__ int2 stage[B1C];
    int t = threadIdx.x;
    int e0 = blockIdx.x * B1C;
    int cnt = min(B1C, NE - e0);
    hist[t] = 0;
    __syncthreads();

    int mykey[8]; int myb[8]; int myw[8]; bool myv[8];
#pragma unroll
    for (int k = 0; k < 8; ++k) {
        int i = t + k * 512;
        myv[k] = (i < cnt);
        if (myv[k]) {
            int e = e0 + i;
            int c = col[e];
            myb[k]   = c >> BKS;
            mykey[k] = (row[e] << BKS) | (c & (BKN - 1));
            myw[k]   = __float_as_int(w[e]);
            atomicAdd(&hist[myb[k]], 1);
        }
    }
    __syncthreads();

    sa[t] = hist[t];
    __syncthreads();
    int* src = sa; int* dst = sb;
#pragma unroll
    for (int off = 1; off < 512; off <<= 1) {
        dst[t] = src[t] + ((t >= off) ? src[t - off] : 0);
        __syncthreads();
        int* tq = src; src = dst; dst = tq;
    }
    int lex = src[t] - hist[t];
    lbase[t] = lex;
    lcur[t]  = lex;
    gbase[t] = (t < NBK && hist[t] > 0) ? atomicAdd(&bkcur[t], hist[t]) : 0;
    __syncthreads();

#pragma unroll
    for (int k = 0; k < 8; ++k) {
        if (myv[k]) {
            int pos = atomicAdd(&lcur[myb[k]], 1);
            stage[pos] = make_int2(mykey[k], myw[k]);
        }
    }
    __syncthreads();

    for (int i = t; i < cnt; i += 512) {
        int lo = 0, hi = NBK;
        while (hi - lo > 1) {
            int mid = (lo + hi) >> 1;
            if (lbase[mid] <= i) lo = mid; else hi = mid;
        }
        tmp[gbase[lo] + (i - lbase[lo])] = stage[i];
    }
}

// ---------------- pass 2: per-bucket node sort in LDS + CSR + dinv ----------------

__global__ __launch_bounds__(256) void k_bucket2(const int* __restrict__ bkbase,
                                                 const int2* __restrict__ tmp,
                                                 int2* __restrict__ sedge,
                                                 int* __restrict__ incl,
                                                 float* __restrict__ dinv) {
    __shared__ int2 stage[CAP2];
    __shared__ int2 sorted[CAP2];
    __shared__ int hist[BKN];
    __shared__ int sa[BKN], sb[BKN];
    __shared__ int lcur[BKN];
    int b = blockIdx.x;
    int t = threadIdx.x;
    int rbeg = bkbase[b], rend = bkbase[b + 1];
    int cnt = min(rend - rbeg, CAP2);
    if (t < BKN) hist[t] = 0;
    __syncthreads();
    for (int i = t; i < cnt; i += 256) {
        int2 ed = tmp[rbeg + i];
        stage[i] = ed;
        atomicAdd(&hist[ed.x & (BKN - 1)], 1);
    }
    __syncthreads();
    if (t < BKN) sa[t] = hist[t];
    __syncthreads();
    int* src = sa; int* dst = sb;
#pragma unroll
    for (int off = 1; off < BKN; off <<= 1) {
        if (t < BKN) dst[t] = src[t] + ((t >= off) ? src[t - off] : 0);
        __syncthreads();
        int* tq = src; src = dst; dst = tq;
    }
    int node0 = b * BKN;
    int lincl = 0, lexcl = 0;
    if (t < BKN) {
        lincl = src[t];
        lexcl = lincl - hist[t];
        lcur[t] = lexcl;
        if (node0 + t < NN) incl[node0 + t] = rbeg + lincl;
    }
    __syncthreads();
    for (int i = t; i < cnt; i += 256) {
        int2 ed = stage[i];
        int pos = atomicAdd(&lcur[ed.x & (BKN - 1)], 1);
        sorted[pos] = ed;
    }
    __syncthreads();
    if (t < BKN && node0 + t < NN) {
        float s = 1.0f;
        for (int e = lexcl; e < lincl; ++e) s += __int_as_float(sorted[e].y);
        dinv[node0 + t] = rsqrtf(s);
    }
    for (int i = t; i < cnt; i += 256) {
        int2 ed = sorted[i];
        sedge[rbeg + i] = make_int2(ed.x >> BKS, ed.y);   // {src, raw weight}
    }
}

// norm = dinv[src] * w * dinv[dst], in-place; 16 lanes per node (coalesced)
__global__ __launch_bounds__(256) void k_snorm(const int* __restrict__ incl,
                                               int2* __restrict__ sedge,
                                               const float* __restrict__ dinv) {
    int node = blockIdx.x * 16 + (threadIdx.x >> 4);
    if (node >= NN) return;
    int fg = threadIdx.x & 15;
    int beg = (node == 0) ? 0 : incl[node - 1];
    int end = incl[node];
    float dc = dinv[node];
    for (int e = beg + fg; e < end; e += 16) {
        int2 ed = sedge[e];
        ed.y = __float_as_int(dinv[ed.x] * __int_as_float(ed.y) * dc);
        sedge[e] = ed;
    }
}

// ---------------- dense: Y[n,64] = X[n,64] @ W[64,64] -> bf16 half-arrays ----------

template<bool BF>
__global__ __launch_bounds__(256) void k_mm64(const void* __restrict__ Xlo,
                                              const void* __restrict__ Xhi,
                                              const float* __restrict__ W,
                                              u16* __restrict__ Ylo,
                                              u16* __restrict__ Yhi) {
    __shared__ float sW[64 * 64];
    __shared__ float sX[16][64];
    int tid = threadIdx.x;
    int c  = tid & 63;
    int wv = tid >> 6;
    for (int i = tid; i < 64 * 64; i += 256) sW[i] = W[i];
    int r0 = blockIdx.x * 16;
#pragma unroll
    for (int i = tid; i < 16 * 64; i += 256) {
        int rr = i >> 6, cc = i & 63;
        float v;
        if (BF) {
            v = (cc < 32) ? bf2f(((const u16*)Xlo)[(size_t)(r0 + rr) * 32 + cc])
                          : bf2f(((const u16*)Xhi)[(size_t)(r0 + rr) * 32 + cc - 32]);
        } else {
            v = ((const float*)Xlo)[(size_t)(r0 + rr) * 64 + cc];
        }
        sX[rr][cc] = v;
    }
    __syncthreads();
    int rb = wv * 4;
    float a0 = 0.f, a1 = 0.f, a2 = 0.f, a3 = 0.f;
#pragma unroll
    for (int k = 0; k < 64; k += 4) {
        float4 x0 = *(const float4*)&sX[rb + 0][k];
        float4 x1 = *(const float4*)&sX[rb + 1][k];
        float4 x2 = *(const float4*)&sX[rb + 2][k];
        float4 x3 = *(const float4*)&sX[rb + 3][k];
        float wA = sW[(k + 0) * 64 + c];
        float wB = sW[(k + 1) * 64 + c];
        float wC = sW[(k + 2) * 64 + c];
        float wD = sW[(k + 3) * 64 + c];
        a0 += x0.x * wA + x0.y * wB + x0.z * wC + x0.w * wD;
        a1 += x1.x * wA + x1.y * wB + x1.z * wC + x1.w * wD;
        a2 += x2.x * wA + x2.y * wB + x2.z * wC + x2.w * wD;
        a3 += x3.x * wA + x3.y * wB + x3.z * wC + x3.w * wD;
    }
    u16* Yp = (c < 32) ? Ylo : Yhi;
    int  cc = c & 31;
    Yp[(size_t)(r0 + rb + 0) * 32 + cc] = f2bf(a0);
    Yp[(size_t)(r0 + rb + 1) * 32 + cc] = f2bf(a1);
    Yp[(size_t)(r0 + rb + 2) * 32 + cc] = f2bf(a2);
    Yp[(size_t)(r0 + rb + 3) * 32 + cc] = f2bf(a3);
}

// ---------------- aggregation over feature HALVES ----------------
// grid = 25000 blocks: [0,12500) -> half lo, [12500,25000) -> half hi.
// Each wave: one node, 32 features. 8 edge slots x 8 feature groups of 4.
// Working set per half = 3.2 MB -> fits per-XCD L2.

__global__ __launch_bounds__(256) void k_agg(const u16* __restrict__ Alo,
                                             const u16* __restrict__ Ahi,
                                             const int* __restrict__ incl,
                                             const int2* __restrict__ sedge,
                                             const float* __restrict__ dinv,
                                             const float* __restrict__ bias,
                                             u16* __restrict__ Blo,
                                             u16* __restrict__ Bhi) {
    int tid  = threadIdx.x;
    int wv   = tid >> 6;
    int bid  = blockIdx.x;
    int half = (bid >= 12500) ? 1 : 0;
    int nb   = bid - half * 12500;
    int node = nb * 4 + wv;                 // < 50000 exact
    const u16* A = half ? Ahi : Alo;
    u16*       B = half ? Bhi : Blo;
    const float* bs = bias + half * 32;
    int lane = tid & 63;
    int slot = lane >> 3;                   // 0..7 edge slot
    int fg   = lane & 7;                    // features fg*4 .. fg*4+3 (within half)
    int beg = (node == 0) ? 0 : incl[node - 1];
    int end = incl[node];
    int deg = end - beg;
    float a0 = 0.f, a1 = 0.f, a2 = 0.f, a3 = 0.f;
    for (int base = 0; base < deg; base += 64) {
        int i = base + lane;
        int2 ed = (i < deg) ? sedge[beg + i] : make_int2(0, 0);   // norm=0 pad
        int m = min(64, deg - base);
        int steps = (m + 7) >> 3;
        for (int t = 0; t < steps; ++t) {
            int idx = (t << 3) + slot;
            int   s  = __shfl(ed.x, idx);
            float nm = __int_as_float(__shfl(ed.y, idx));   // full norm (k_snorm)
            const ushort4v a = *(const ushort4v*)(A + (size_t)s * 32 + (fg << 2));
            a0 += bf2f(a[0]) * nm;
            a1 += bf2f(a[1]) * nm;
            a2 += bf2f(a[2]) * nm;
            a3 += bf2f(a[3]) * nm;
        }
    }
    // reduce across 8 slots (xor 8, 16, 32)
#pragma unroll
    for (int o = 8; o <= 32; o <<= 1) {
        a0 += __shfl_xor(a0, o);
        a1 += __shfl_xor(a1, o);
        a2 += __shfl_xor(a2, o);
        a3 += __shfl_xor(a3, o);
    }
    if (slot == 0) {
        float d = dinv[node];
        float d2 = d * d;
        const ushort4v self = *(const ushort4v*)(A + (size_t)node * 32 + (fg << 2));
        const float4 bb = *(const float4*)(bs + (fg << 2));
        ushort4v ov;
        ov[0] = f2bf(fmaxf(a0 + bf2f(self[0]) * d2 + bb.x, 0.f));
        ov[1] = f2bf(fmaxf(a1 + bf2f(self[1]) * d2 + bb.y, 0.f));
        ov[2] = f2bf(fmaxf(a2 + bf2f(self[2]) * d2 + bb.z, 0.f));
        ov[3] = f2bf(fmaxf(a3 + bf2f(self[3]) * d2 + bb.w, 0.f));
        *(ushort4v*)(B + (size_t)node * 32 + (fg << 2)) = ov;
    }
}

// ---------------- head: softmax(H @ Wout + bout), H in bf16 half-arrays ----------

__global__ __launch_bounds__(256) void k_out(const u16* __restrict__ Hlo,
                                             const u16* __restrict__ Hhi,
                                             const float* __restrict__ Wout,
                                             const float* __restrict__ bout,
                                             float* __restrict__ out) {
    __shared__ float sW[64 * NCLS];
    __shared__ float sb[NCLS];
    for (int i = threadIdx.x; i < 64 * NCLS; i += 256) sW[i] = Wout[i];
    if (threadIdx.x < NCLS) sb[threadIdx.x] = bout[threadIdx.x];
    __syncthreads();
    int lr = threadIdx.x >> 4;
    int c  = threadIdx.x & 15;
    int r  = blockIdx.x * 16 + lr;
    const u16* hlo = Hlo + (size_t)r * 32;
    const u16* hhi = Hhi + (size_t)r * 32;
    float acc = sb[c];
#pragma unroll
    for (int k = 0; k < 32; ++k)
        acc += bf2f(hlo[k]) * sW[k * NCLS + c];
#pragma unroll
    for (int k = 0; k < 32; ++k)
        acc += bf2f(hhi[k]) * sW[(k + 32) * NCLS + c];
    float m = acc;
#pragma unroll
    for (int o = 8; o >= 1; o >>= 1) m = fmaxf(m, __shfl_xor(m, o, 16));
    float ex = expf(acc - m);
    float s = ex;
#pragma unroll
    for (int o = 8; o >= 1; o >>= 1) s += __shfl_xor(s, o, 16);
    out[(size_t)r * NCLS + c] = ex / s;
}

// ---------------- launch ----------------

extern "C" void kernel_launch(void* const* d_in, const int* in_sizes, int n_in,
                              void* d_out, int out_size, void* d_ws, size_t ws_size,
                              hipStream_t stream) {
    const float* x    = (const float*)d_in[0];
    const int*   ei   = (const int*)d_in[1];
    const float* ew   = (const float*)d_in[2];
    const float* W1   = (const float*)d_in[3];
    const float* b1   = (const float*)d_in[4];
    const float* W2   = (const float*)d_in[5];
    const float* b2   = (const float*)d_in[6];
    const float* Wout = (const float*)d_in[7];
    const float* bout = (const float*)d_in[8];
    const int* row = ei;
    const int* col = ei + NE;

    // workspace; tmp aliases feature region (written only after bucket2 consumed tmp)
    int*   ip     = (int*)d_ws;
    int*   incl   = ip;                               // 50048
    float* dinv   = (float*)(ip + 50048);             // 50048
    int*   bkcnt  = ip + 100096;                      // 512
    int*   bkbase = ip + 100608;                      // 512
    int*   bkcur  = ip + 101120;                      // 512
    int2*  sedge  = (int2*)(ip + 101632);             // NE int2
    u16*   feat   = (u16*)(ip + 101632 + 2 * NE);
    u16*   Alo    = feat;                             // NN*32 bf16 = 3.2 MB
    u16*   Ahi    = feat + 1600000;
    u16*   Blo    = feat + 3200000;
    u16*   Bhi    = feat + 4800000;
    int2*  tmp    = (int2*)feat;                      // NE int2 aliased over A/B region

    // sort pipeline
    k_zeroi<<<2, 256, 0, stream>>>(bkcnt, 512);
    k_bkhist<<<B1B, 256, 0, stream>>>(col, bkcnt);
    k_scan_bk<<<1, 512, 0, stream>>>(bkcnt, bkbase, bkcur);
    k_bucket1<<<B1B, 512, 0, stream>>>(row, col, ew, bkcur, tmp);
    k_bucket2<<<NBK, 256, 0, stream>>>(bkbase, tmp, sedge, incl, dinv);
    k_snorm<<<(NN + 15) / 16, 256, 0, stream>>>(incl, sedge, dinv);

    // layer 1
    k_mm64<false><<<NN / 16, 256, 0, stream>>>(x, nullptr, W1, Alo, Ahi);
    k_agg<<<25000, 256, 0, stream>>>(Alo, Ahi, incl, sedge, dinv, b1, Blo, Bhi);

    // layer 2
    k_mm64<true><<<NN / 16, 256, 0, stream>>>(Blo, Bhi, W2, Alo, Ahi);
    k_agg<<<25000, 256, 0, stream>>>(Alo, Ahi, incl, sedge, dinv, b2, Blo, Bhi);

    // head
    k_out<<<NN / 16, 256, 0, stream>>>(Blo, Bhi, Wout, bout, (float*)d_out);
}

// Round 7
// 223.495 us; speedup vs baseline: 1.0737x; 1.0737x over previous
//
#include <hip/hip_runtime.h>
#include <math.h>

#define NN 50000
#define NE 800000
#define F 64
#define NCLS 16

#define BKS 7              // log2(nodes per bucket)
#define BKN 128            // nodes per bucket
#define NBK 391            // ceil(50000/128)
#define B1C 4096           // edges per bucket1 block
#define B1B 196            // ceil(NE/B1C)
#define CAP2 3072          // max edges per bucket

typedef unsigned short u16;
typedef __attribute__((ext_vector_type(8))) unsigned short ushort8v;

__device__ __forceinline__ float bf2f(u16 h) {
    return __uint_as_float((unsigned)h << 16);
}
__device__ __forceinline__ u16 f2bf(float f) {   // round-nearest-even
    unsigned u = __float_as_uint(f);
    return (u16)((u + 0x7fffu + ((u >> 16) & 1u)) >> 16);
}

__global__ void k_zeroi(int* __restrict__ p, int n) {
    int i = blockIdx.x * 256 + threadIdx.x;
    if (i < n) p[i] = 0;
}

// ---------------- pass 0: coarse bucket histogram ----------------

__global__ __launch_bounds__(256) void k_bkhist(const int* __restrict__ col,
                                                int* __restrict__ bkcnt) {
    __shared__ int h[NBK];
    for (int i = threadIdx.x; i < NBK; i += 256) h[i] = 0;
    __syncthreads();
    int stride = gridDim.x * 256;
    for (int e = blockIdx.x * 256 + threadIdx.x; e < NE; e += stride)
        atomicAdd(&h[col[e] >> BKS], 1);
    __syncthreads();
    for (int i = threadIdx.x; i < NBK; i += 256) {
        int v = h[i];
        if (v) atomicAdd(&bkcnt[i], v);
    }
}

// ---------------- scan bucket counts -> bases + cursors (1 block) ----------------

__global__ __launch_bounds__(512) void k_scan_bk(const int* __restrict__ bkcnt,
                                                 int* __restrict__ bkbase,
                                                 int* __restrict__ bkcur) {
    __shared__ int sa[512], sb[512];
    int t = threadIdx.x;
    int c = (t < NBK) ? bkcnt[t] : 0;
    sa[t] = c;
    __syncthreads();
    int* src = sa; int* dst = sb;
#pragma unroll
    for (int off = 1; off < 512; off <<= 1) {
        dst[t] = src[t] + ((t >= off) ? src[t - off] : 0);
        __syncthreads();
        int* tq = src; src = dst; dst = tq;
    }
    if (t < NBK) {
        int excl = src[t] - c;
        bkbase[t] = excl;
        bkcur[t]  = excl;
    }
    if (t == NBK) bkbase[t] = NE;
}

// ---------------- pass 1: group edges by bucket (LDS), flush contiguous runs ------

__global__ __launch_bounds__(512) void k_bucket1(const int* __restrict__ row,
                                                 const int* __restrict__ col,
                                                 const float* __restrict__ w,
                                                 int* __restrict__ bkcur,
                                                 int2* __restrict__ tmp) {
    __shared__ int hist[512];
    __shared__ int sa[512], sb[512];
    __shared__ int lbase[512];
    __shared__ int gbase[512];
    __shared__ int lcur[512];
    __shared__ int2 stage[B1C];
    int t = threadIdx.x;
    int e0 = blockIdx.x * B1C;
    int cnt = min(B1C, NE - e0);
    hist[t] = 0;
    __syncthreads();

    int mykey[8]; int myb[8]; int myw[8]; bool myv[8];
#pragma unroll
    for (int k = 0; k < 8; ++k) {
        int i = t + k * 512;
        myv[k] = (i < cnt);
        if (myv[k]) {
            int e = e0 + i;
            int c = col[e];
            myb[k]   = c >> BKS;
            mykey[k] = (row[e] << BKS) | (c & (BKN - 1));
            myw[k]   = __float_as_int(w[e]);
            atomicAdd(&hist[myb[k]], 1);
        }
    }
    __syncthreads();

    sa[t] = hist[t];
    __syncthreads();
    int* src = sa; int* dst = sb;
#pragma unroll
    for (int off = 1; off < 512; off <<= 1) {
        dst[t] = src[t] + ((t >= off) ? src[t - off] : 0);
        __syncthreads();
        int* tq = src; src = dst; dst = tq;
    }
    int lex = src[t] - hist[t];
    lbase[t] = lex;
    lcur[t]  = lex;
    gbase[t] = (t < NBK && hist[t] > 0) ? atomicAdd(&bkcur[t], hist[t]) : 0;
    __syncthreads();

#pragma unroll
    for (int k = 0; k < 8; ++k) {
        if (myv[k]) {
            int pos = atomicAdd(&lcur[myb[k]], 1);
            stage[pos] = make_int2(mykey[k], myw[k]);
        }
    }
    __syncthreads();

    for (int i = t; i < cnt; i += 512) {
        int lo = 0, hi = NBK;
        while (hi - lo > 1) {
            int mid = (lo + hi) >> 1;
            if (lbase[mid] <= i) lo = mid; else hi = mid;
        }
        tmp[gbase[lo] + (i - lbase[lo])] = stage[i];
    }
}

// ---------------- pass 2: per-bucket node sort in LDS + CSR + dinv ----------------

__global__ __launch_bounds__(256) void k_bucket2(const int* __restrict__ bkbase,
                                                 const int2* __restrict__ tmp,
                                                 int2* __restrict__ sedge,
                                                 int* __restrict__ incl,
                                                 float* __restrict__ dinv) {
    __shared__ int2 stage[CAP2];
    __shared__ int2 sorted[CAP2];
    __shared__ int hist[BKN];
    __shared__ int sa[BKN], sb[BKN];
    __shared__ int lcur[BKN];
    int b = blockIdx.x;
    int t = threadIdx.x;
    int rbeg = bkbase[b], rend = bkbase[b + 1];
    int cnt = min(rend - rbeg, CAP2);
    if (t < BKN) hist[t] = 0;
    __syncthreads();
    for (int i = t; i < cnt; i += 256) {
        int2 ed = tmp[rbeg + i];
        stage[i] = ed;
        atomicAdd(&hist[ed.x & (BKN - 1)], 1);
    }
    __syncthreads();
    if (t < BKN) sa[t] = hist[t];
    __syncthreads();
    int* src = sa; int* dst = sb;
#pragma unroll
    for (int off = 1; off < BKN; off <<= 1) {
        if (t < BKN) dst[t] = src[t] + ((t >= off) ? src[t - off] : 0);
        __syncthreads();
        int* tq = src; src = dst; dst = tq;
    }
    int node0 = b * BKN;
    int lincl = 0, lexcl = 0;
    if (t < BKN) {
        lincl = src[t];
        lexcl = lincl - hist[t];
        lcur[t] = lexcl;
        if (node0 + t < NN) incl[node0 + t] = rbeg + lincl;
    }
    __syncthreads();
    for (int i = t; i < cnt; i += 256) {
        int2 ed = stage[i];
        int pos = atomicAdd(&lcur[ed.x & (BKN - 1)], 1);
        sorted[pos] = ed;
    }
    __syncthreads();
    if (t < BKN && node0 + t < NN) {
        float s = 1.0f;
        for (int e = lexcl; e < lincl; ++e) s += __int_as_float(sorted[e].y);
        dinv[node0 + t] = rsqrtf(s);
    }
    for (int i = t; i < cnt; i += 256) {
        int2 ed = sorted[i];
        sedge[rbeg + i] = make_int2(ed.x >> BKS, ed.y);   // {src, raw weight}
    }
}

// norm = dinv[src] * w * dinv[dst], in-place; 16 lanes per node (coalesced)
__global__ __launch_bounds__(256) void k_snorm(const int* __restrict__ incl,
                                               int2* __restrict__ sedge,
                                               const float* __restrict__ dinv) {
    int node = blockIdx.x * 16 + (threadIdx.x >> 4);
    if (node >= NN) return;
    int fg = threadIdx.x & 15;
    int beg = (node == 0) ? 0 : incl[node - 1];
    int end = incl[node];
    float dc = dinv[node];
    for (int e = beg + fg; e < end; e += 16) {
        int2 ed = sedge[e];
        ed.y = __float_as_int(dinv[ed.x] * __int_as_float(ed.y) * dc);
        sedge[e] = ed;
    }
}

// ---------------- dense: Y[n,64] = X[n,64] @ W[64,64] -> bf16 ----------------

template<bool BF>
__global__ __launch_bounds__(256) void k_mm64(const void* __restrict__ Xv,
                                              const float* __restrict__ W,
                                              u16* __restrict__ Y) {
    __shared__ float sW[64 * 64];
    __shared__ float sX[16][64];
    int tid = threadIdx.x;
    int c  = tid & 63;
    int wv = tid >> 6;
    for (int i = tid; i < 64 * 64; i += 256) sW[i] = W[i];
    int r0 = blockIdx.x * 16;
#pragma unroll
    for (int i = tid; i < 16 * 64; i += 256) {
        size_t idx = (size_t)(r0 + (i >> 6)) * 64 + (i & 63);
        if (BF) sX[i >> 6][i & 63] = bf2f(((const u16*)Xv)[idx]);
        else    sX[i >> 6][i & 63] = ((const float*)Xv)[idx];
    }
    __syncthreads();
    int rb = wv * 4;
    float a0 = 0.f, a1 = 0.f, a2 = 0.f, a3 = 0.f;
#pragma unroll
    for (int k = 0; k < 64; k += 4) {
        float4 x0 = *(const float4*)&sX[rb + 0][k];
        float4 x1 = *(const float4*)&sX[rb + 1][k];
        float4 x2 = *(const float4*)&sX[rb + 2][k];
        float4 x3 = *(const float4*)&sX[rb + 3][k];
        float wA = sW[(k + 0) * 64 + c];
        float wB = sW[(k + 1) * 64 + c];
        float wC = sW[(k + 2) * 64 + c];
        float wD = sW[(k + 3) * 64 + c];
        a0 += x0.x * wA + x0.y * wB + x0.z * wC + x0.w * wD;
        a1 += x1.x * wA + x1.y * wB + x1.z * wC + x1.w * wD;
        a2 += x2.x * wA + x2.y * wB + x2.z * wC + x2.w * wD;
        a3 += x3.x * wA + x3.y * wB + x3.z * wC + x3.w * wD;
    }
    Y[(size_t)(r0 + rb + 0) * 64 + c] = f2bf(a0);
    Y[(size_t)(r0 + rb + 1) * 64 + c] = f2bf(a1);
    Y[(size_t)(r0 + rb + 2) * 64 + c] = f2bf(a2);
    Y[(size_t)(r0 + rb + 3) * 64 + c] = f2bf(a3);
}

// ---------------- aggregation: one wave/node, bf16 gather, 8 edges in flight ----
// norm PRE-BAKED in sedge.y by k_snorm (no in-loop dinv gather).
// HEAD: fuse logits @ Wout + bout + softmax -> out

template<bool HEAD>
__global__ __launch_bounds__(256) void k_agg(const u16* __restrict__ A,
                                             const int* __restrict__ incl,
                                             const int2* __restrict__ sedge,
                                             const float* __restrict__ dinv,
                                             const float* __restrict__ bias,
                                             u16* __restrict__ B,
                                             const float* __restrict__ Wout,
                                             const float* __restrict__ bout,
                                             float* __restrict__ out) {
    __shared__ float sWout[64 * NCLS];
    __shared__ float sh[4][64];
    int tid  = threadIdx.x;
    int wv   = tid >> 6;
    int node = blockIdx.x * 4 + wv;       // 12500*4 = 50000 exact
    int lane = tid & 63;
    int slot = lane >> 3;                 // 0..7 edge slot
    int fg   = lane & 7;                  // features fg*8 .. fg*8+7
    if (HEAD) {
        for (int i = tid; i < 64 * NCLS; i += 256) sWout[i] = Wout[i];
    }
    int beg = (node == 0) ? 0 : incl[node - 1];
    int end = incl[node];
    int deg = end - beg;
    float acc[8] = {0.f, 0.f, 0.f, 0.f, 0.f, 0.f, 0.f, 0.f};
    for (int base = 0; base < deg; base += 64) {
        int i = base + lane;
        int2 ed = (i < deg) ? sedge[beg + i] : make_int2(0, 0);  // norm=0 pad
        int m = min(64, deg - base);
        int steps = (m + 7) >> 3;
        for (int t = 0; t < steps; ++t) {
            int idx = (t << 3) + slot;
            int   s  = __shfl(ed.x, idx);
            float nm = __int_as_float(__shfl(ed.y, idx));   // final norm
            const ushort8v a = *(const ushort8v*)(A + (size_t)s * 64 + (fg << 3));
#pragma unroll
            for (int j = 0; j < 8; ++j) acc[j] += bf2f(a[j]) * nm;
        }
    }
    // reduce across 8 slots
#pragma unroll
    for (int o = 8; o <= 32; o <<= 1) {
#pragma unroll
        for (int j = 0; j < 8; ++j) acc[j] += __shfl_xor(acc[j], o);
    }
    if (slot == 0) {
        float d = dinv[node];
        float d2 = d * d;
        const ushort8v self = *(const ushort8v*)(A + (size_t)node * 64 + (fg << 3));
        const float4 bb0 = *(const float4*)(bias + (fg << 3));
        const float4 bb1 = *(const float4*)(bias + (fg << 3) + 4);
        float bbv[8] = {bb0.x, bb0.y, bb0.z, bb0.w, bb1.x, bb1.y, bb1.z, bb1.w};
        ushort8v ov;
#pragma unroll
        for (int j = 0; j < 8; ++j) {
            float v = fmaxf(acc[j] + bf2f(self[j]) * d2 + bbv[j], 0.f);
            ov[j] = f2bf(v);
            if (HEAD) sh[wv][(fg << 3) + j] = v;
        }
        *(ushort8v*)(B + (size_t)node * 64 + (fg << 3)) = ov;
    }
    if (HEAD) {
        __syncthreads();
        int c = lane & 15, q = lane >> 4;
        float p = 0.f;
#pragma unroll
        for (int k = 0; k < 16; ++k)
            p += sh[wv][q * 16 + k] * sWout[(q * 16 + k) * NCLS + c];
        p += __shfl_xor(p, 16);
        p += __shfl_xor(p, 32);
        p += bout[c];
        float mx = p;
#pragma unroll
        for (int o = 8; o >= 1; o >>= 1) mx = fmaxf(mx, __shfl_xor(mx, o, 16));
        float ex = expf(p - mx);
        float s = ex;
#pragma unroll
        for (int o = 8; o >= 1; o >>= 1) s += __shfl_xor(s, o, 16);
        if (lane < 16) out[(size_t)node * NCLS + c] = ex / s;
    }
}

// ---------------- launch ----------------

extern "C" void kernel_launch(void* const* d_in, const int* in_sizes, int n_in,
                              void* d_out, int out_size, void* d_ws, size_t ws_size,
                              hipStream_t stream) {
    const float* x    = (const float*)d_in[0];
    const int*   ei   = (const int*)d_in[1];
    const float* ew   = (const float*)d_in[2];
    const float* W1   = (const float*)d_in[3];
    const float* b1   = (const float*)d_in[4];
    const float* W2   = (const float*)d_in[5];
    const float* b2   = (const float*)d_in[6];
    const float* Wout = (const float*)d_in[7];
    const float* bout = (const float*)d_in[8];
    const int* row = ei;
    const int* col = ei + NE;

    // workspace; tmp aliases A+B region (A/B written only after bucket2 consumed tmp)
    int*   ip     = (int*)d_ws;
    int*   incl   = ip;                               // 50048
    float* dinv   = (float*)(ip + 50048);             // 50048
    int*   bkcnt  = ip + 100096;                      // 512
    int*   bkbase = ip + 100608;                      // 512
    int*   bkcur  = ip + 101120;                      // 512
    int2*  sedge  = (int2*)(ip + 101632);             // NE int2
    u16*   A      = (u16*)(ip + 101632 + 2 * NE);     // NN*64 bf16
    u16*   B      = A + 3200000;
    int2*  tmp    = (int2*)A;                         // NE int2 aliased over A+B

    // sort pipeline
    k_zeroi<<<2, 256, 0, stream>>>(bkcnt, 512);
    k_bkhist<<<B1B, 256, 0, stream>>>(col, bkcnt);
    k_scan_bk<<<1, 512, 0, stream>>>(bkcnt, bkbase, bkcur);
    k_bucket1<<<B1B, 512, 0, stream>>>(row, col, ew, bkcur, tmp);
    k_bucket2<<<NBK, 256, 0, stream>>>(bkbase, tmp, sedge, incl, dinv);
    k_snorm<<<(NN + 15) / 16, 256, 0, stream>>>(incl, sedge, dinv);

    // layer 1
    k_mm64<false><<<NN / 16, 256, 0, stream>>>(x, W1, A);
    k_agg<false><<<NN / 4, 256, 0, stream>>>(A, incl, sedge, dinv, b1, B,
                                             nullptr, nullptr, nullptr);
    // layer 2 + fused head
    k_mm64<true><<<NN / 16, 256, 0, stream>>>(B, W2, A);
    k_agg<true><<<NN / 4, 256, 0, stream>>>(A, incl, sedge, dinv, b2, B,
                                            Wout, bout, (float*)d_out);
}

// Round 8
// 188.202 us; speedup vs baseline: 1.2750x; 1.1875x over previous
//
#include <hip/hip_runtime.h>
#include <math.h>

#define NN 50000
#define NE 800000
#define F 64
#define NCLS 16

#define BKS 7              // log2(nodes per bucket)
#define BKN 128            // nodes per bucket
#define NBK 391            // ceil(50000/128)
#define CAP 2560           // slots per bucket region (avg 2048, sigma~45 -> +11 sigma)
#define B1C 4096           // edges per bucket1 block
#define B1B 196            // ceil(NE/B1C)
#define CAP2 3072          // bucket2 LDS capacity

typedef unsigned short u16;
typedef __attribute__((ext_vector_type(8))) unsigned short ushort8v;

__device__ __forceinline__ float bf2f(u16 h) {
    return __uint_as_float((unsigned)h << 16);
}
__device__ __forceinline__ u16 f2bf(float f) {   // round-nearest-even
    unsigned u = __float_as_uint(f);
    return (u16)((u + 0x7fffu + ((u >> 16) & 1u)) >> 16);
}

// cursors start at the region bases: cur[b] = b*CAP
__global__ void k_init_cur(int* __restrict__ cur) {
    int b = blockIdx.x * 256 + threadIdx.x;
    if (b < NBK) cur[b] = b * CAP;
}

// ---------------- pass 1: group edges by bucket (LDS), flush runs to slotted regions

__global__ __launch_bounds__(512) void k_bucket1(const int* __restrict__ row,
                                                 const int* __restrict__ col,
                                                 const float* __restrict__ w,
                                                 int* __restrict__ bkcur,
                                                 int2* __restrict__ tmp) {
    __shared__ int hist[512];
    __shared__ int sa[512], sb[512];
    __shared__ int lbase[512];
    __shared__ int gbase[512];
    __shared__ int lcur[512];
    __shared__ int2 stage[B1C];
    int t = threadIdx.x;
    int e0 = blockIdx.x * B1C;
    int cnt = min(B1C, NE - e0);
    hist[t] = 0;
    __syncthreads();

    int mykey[8]; int myb[8]; int myw[8]; bool myv[8];
#pragma unroll
    for (int k = 0; k < 8; ++k) {
        int i = t + k * 512;
        myv[k] = (i < cnt);
        if (myv[k]) {
            int e = e0 + i;
            int c = col[e];
            myb[k]   = c >> BKS;
            mykey[k] = (row[e] << BKS) | (c & (BKN - 1));
            myw[k]   = __float_as_int(w[e]);
            atomicAdd(&hist[myb[k]], 1);
        }
    }
    __syncthreads();

    sa[t] = hist[t];
    __syncthreads();
    int* src = sa; int* dst = sb;
#pragma unroll
    for (int off = 1; off < 512; off <<= 1) {
        dst[t] = src[t] + ((t >= off) ? src[t - off] : 0);
        __syncthreads();
        int* tq = src; src = dst; dst = tq;
    }
    int lex = src[t] - hist[t];
    lbase[t] = lex;
    lcur[t]  = lex;
    gbase[t] = (t < NBK && hist[t] > 0) ? atomicAdd(&bkcur[t], hist[t]) : 0;
    __syncthreads();

#pragma unroll
    for (int k = 0; k < 8; ++k) {
        if (myv[k]) {
            int pos = atomicAdd(&lcur[myb[k]], 1);
            stage[pos] = make_int2(mykey[k], myw[k]);
        }
    }
    __syncthreads();

    // flush: element i belongs to run r with lbase[r] <= i < lbase[r+1]
    for (int i = t; i < cnt; i += 512) {
        int lo = 0, hi = NBK;
        while (hi - lo > 1) {
            int mid = (lo + hi) >> 1;
            if (lbase[mid] <= i) lo = mid; else hi = mid;
        }
        tmp[gbase[lo] + (i - lbase[lo])] = stage[i];
    }
}

// ---------------- pass 2: per-bucket node sort in LDS + beg/end + dinv ----------------

__global__ __launch_bounds__(256) void k_bucket2(const int* __restrict__ bkcur,
                                                 const int2* __restrict__ tmp,
                                                 int2* __restrict__ sedge,
                                                 int* __restrict__ begA,
                                                 int* __restrict__ endA,
                                                 float* __restrict__ dinv) {
    __shared__ int2 stage[CAP2];
    __shared__ int2 sorted[CAP2];
    __shared__ int hist[BKN];
    __shared__ int sa[BKN], sb[BKN];
    __shared__ int lcur[BKN];
    int b = blockIdx.x;
    int t = threadIdx.x;
    int rbeg = b * CAP;
    int cnt = min(bkcur[b] - rbeg, CAP2);
    if (t < BKN) hist[t] = 0;
    __syncthreads();
    for (int i = t; i < cnt; i += 256) {
        int2 ed = tmp[rbeg + i];
        stage[i] = ed;
        atomicAdd(&hist[ed.x & (BKN - 1)], 1);
    }
    __syncthreads();
    if (t < BKN) sa[t] = hist[t];
    __syncthreads();
    int* src = sa; int* dst = sb;
#pragma unroll
    for (int off = 1; off < BKN; off <<= 1) {
        if (t < BKN) dst[t] = src[t] + ((t >= off) ? src[t - off] : 0);
        __syncthreads();
        int* tq = src; src = dst; dst = tq;
    }
    int node0 = b * BKN;
    int lincl = 0, lexcl = 0;
    if (t < BKN) {
        lincl = src[t];
        lexcl = lincl - hist[t];
        lcur[t] = lexcl;
        if (node0 + t < NN) {
            begA[node0 + t] = rbeg + lexcl;
            endA[node0 + t] = rbeg + lincl;
        }
    }
    __syncthreads();
    for (int i = t; i < cnt; i += 256) {
        int2 ed = stage[i];
        int pos = atomicAdd(&lcur[ed.x & (BKN - 1)], 1);
        sorted[pos] = ed;
    }
    __syncthreads();
    if (t < BKN && node0 + t < NN) {
        float s = 1.0f;      // self-loop weight
        for (int e = lexcl; e < lincl; ++e) s += __int_as_float(sorted[e].y);
        dinv[node0 + t] = rsqrtf(s);
    }
    for (int i = t; i < cnt; i += 256) {
        int2 ed = sorted[i];
        sedge[rbeg + i] = make_int2(ed.x >> BKS, ed.y);   // {src, raw weight}
    }
}

// ---------------- dense: Y[n,64] = X[n,64] @ W[64,64] -> bf16 ----------------

template<bool BF>
__global__ __launch_bounds__(256) void k_mm64(const void* __restrict__ Xv,
                                              const float* __restrict__ W,
                                              u16* __restrict__ Y) {
    __shared__ float sW[64 * 64];
    __shared__ float sX[16][64];
    int tid = threadIdx.x;
    int c  = tid & 63;
    int wv = tid >> 6;
    for (int i = tid; i < 64 * 64; i += 256) sW[i] = W[i];
    int r0 = blockIdx.x * 16;
#pragma unroll
    for (int i = tid; i < 16 * 64; i += 256) {
        size_t idx = (size_t)(r0 + (i >> 6)) * 64 + (i & 63);
        if (BF) sX[i >> 6][i & 63] = bf2f(((const u16*)Xv)[idx]);
        else    sX[i >> 6][i & 63] = ((const float*)Xv)[idx];
    }
    __syncthreads();
    int rb = wv * 4;
    float a0 = 0.f, a1 = 0.f, a2 = 0.f, a3 = 0.f;
#pragma unroll
    for (int k = 0; k < 64; k += 4) {
        float4 x0 = *(const float4*)&sX[rb + 0][k];
        float4 x1 = *(const float4*)&sX[rb + 1][k];
        float4 x2 = *(const float4*)&sX[rb + 2][k];
        float4 x3 = *(const float4*)&sX[rb + 3][k];
        float wA = sW[(k + 0) * 64 + c];
        float wB = sW[(k + 1) * 64 + c];
        float wC = sW[(k + 2) * 64 + c];
        float wD = sW[(k + 3) * 64 + c];
        a0 += x0.x * wA + x0.y * wB + x0.z * wC + x0.w * wD;
        a1 += x1.x * wA + x1.y * wB + x1.z * wC + x1.w * wD;
        a2 += x2.x * wA + x2.y * wB + x2.z * wC + x2.w * wD;
        a3 += x3.x * wA + x3.y * wB + x3.z * wC + x3.w * wD;
    }
    Y[(size_t)(r0 + rb + 0) * 64 + c] = f2bf(a0);
    Y[(size_t)(r0 + rb + 1) * 64 + c] = f2bf(a1);
    Y[(size_t)(r0 + rb + 2) * 64 + c] = f2bf(a2);
    Y[(size_t)(r0 + rb + 3) * 64 + c] = f2bf(a3);
}

// ---------------- aggregation: TWO nodes per wave ----------------
// half = lane>>5 picks the node; within the 32-lane half: 4 edge slots x 8
// feature-lanes (ushort8 = features fg*8..fg*8+7). Per wave-step: 8 gathered
// rows (4 per half). norm = w * dinv[src] in-loop (measured-neutral vs prebake).
// HEAD: fuse logits @ Wout + bout + softmax -> out.

template<bool HEAD>
__global__ __launch_bounds__(256) void k_agg(const u16* __restrict__ A,
                                             const int* __restrict__ begA,
                                             const int* __restrict__ endA,
                                             const int2* __restrict__ sedge,
                                             const float* __restrict__ dinv,
                                             const float* __restrict__ bias,
                                             u16* __restrict__ B,
                                             const float* __restrict__ Wout,
                                             const float* __restrict__ bout,
                                             float* __restrict__ out) {
    __shared__ float sWout[64 * NCLS];
    __shared__ float sh[8][64];
    int tid  = threadIdx.x;
    int wv   = tid >> 6;
    int lane = tid & 63;
    int half = lane >> 5;                 // node within the wave
    int sub  = lane & 31;
    int slot = sub >> 3;                  // 0..3 edge slot
    int fg   = sub & 7;                   // features fg*8 .. fg*8+7
    int node = blockIdx.x * 8 + wv * 2 + half;   // 6250*8 = 50000 exact
    if (HEAD) {
        for (int i = tid; i < 64 * NCLS; i += 256) sWout[i] = Wout[i];
    }
    int beg = begA[node];
    int deg = endA[node] - beg;
    float acc[8] = {0.f, 0.f, 0.f, 0.f, 0.f, 0.f, 0.f, 0.f};
    for (int base = 0; base < deg; base += 32) {
        int i = base + sub;
        int2 ed = (i < deg) ? sedge[beg + i] : make_int2(0, 0);   // w=0 pad
        float nmr = __int_as_float(ed.y) * dinv[ed.x];            // w * dinv[src]
        int m = min(32, deg - base);
        int steps = (m + 3) >> 2;
        for (int t = 0; t < steps; ++t) {
            int idx = (half << 5) + (t << 2) + slot;   // lane holding edge t*4+slot
            int   s  = __shfl(ed.x, idx);
            float nm = __shfl(nmr, idx);
            const ushort8v a = *(const ushort8v*)(A + (size_t)s * 64 + (fg << 3));
#pragma unroll
            for (int j = 0; j < 8; ++j) acc[j] += bf2f(a[j]) * nm;
        }
    }
    // reduce across the 4 slots within each half (xor 8, 16 stay inside the half)
#pragma unroll
    for (int o = 8; o <= 16; o <<= 1) {
#pragma unroll
        for (int j = 0; j < 8; ++j) acc[j] += __shfl_xor(acc[j], o);
    }
    if (slot == 0) {                       // 8 lanes per half: fg = 0..7
        float d = dinv[node];
        float d2 = d * d;
        const ushort8v self = *(const ushort8v*)(A + (size_t)node * 64 + (fg << 3));
        const float4 bb0 = *(const float4*)(bias + (fg << 3));
        const float4 bb1 = *(const float4*)(bias + (fg << 3) + 4);
        float bbv[8] = {bb0.x, bb0.y, bb0.z, bb0.w, bb1.x, bb1.y, bb1.z, bb1.w};
        ushort8v ov;
#pragma unroll
        for (int j = 0; j < 8; ++j) {
            float v = fmaxf(acc[j] * d + bf2f(self[j]) * d2 + bbv[j], 0.f);
            ov[j] = f2bf(v);
            if (HEAD) sh[wv * 2 + half][(fg << 3) + j] = v;
        }
        *(ushort8v*)(B + (size_t)node * 64 + (fg << 3)) = ov;
    }
    if (HEAD) {
        __syncthreads();
        // 8 nodes/block, 32 threads per node: c = class, q = k-half (32 ks each)
        int nib  = tid >> 5;               // node-in-block 0..7
        int sub2 = tid & 31;
        int c = sub2 & 15, q = sub2 >> 4;
        const float* hrow = sh[nib];
        float p = 0.f;
#pragma unroll
        for (int k = 0; k < 32; ++k)
            p += hrow[q * 32 + k] * sWout[(q * 32 + k) * NCLS + c];
        p += __shfl_xor(p, 16);            // combine the two q halves (same nib)
        p += bout[c];
        float mx = p;
#pragma unroll
        for (int o = 8; o >= 1; o >>= 1) mx = fmaxf(mx, __shfl_xor(mx, o, 16));
        float ex = expf(p - mx);
        float s = ex;
#pragma unroll
        for (int o = 8; o >= 1; o >>= 1) s += __shfl_xor(s, o, 16);
        if (q == 0) out[(size_t)(blockIdx.x * 8 + nib) * NCLS + c] = ex / s;
    }
}

// ---------------- launch ----------------

extern "C" void kernel_launch(void* const* d_in, const int* in_sizes, int n_in,
                              void* d_out, int out_size, void* d_ws, size_t ws_size,
                              hipStream_t stream) {
    const float* x    = (const float*)d_in[0];
    const int*   ei   = (const int*)d_in[1];
    const float* ew   = (const float*)d_in[2];
    const float* W1   = (const float*)d_in[3];
    const float* b1   = (const float*)d_in[4];
    const float* W2   = (const float*)d_in[5];
    const float* b2   = (const float*)d_in[6];
    const float* Wout = (const float*)d_in[7];
    const float* bout = (const float*)d_in[8];
    const int* row = ei;
    const int* col = ei + NE;

    // workspace; tmp aliases the A/B feature region (consumed by bucket2 first)
    int*   ip     = (int*)d_ws;
    int*   begA   = ip;                               // 50048
    int*   endA   = ip + 50048;                       // 50048
    float* dinv   = (float*)(ip + 100096);            // 50048
    int*   bkcur  = ip + 150144;                      // 512
    int2*  sedge  = (int2*)(ip + 150656);             // NBK*CAP int2 (~8 MB)
    u16*   A      = (u16*)(ip + 150656 + 2 * NBK * CAP);  // NN*64 bf16 (16B aligned)
    u16*   B      = A + 3200000;
    int2*  tmp    = (int2*)A;                         // NBK*CAP int2 aliased over A+B

    // sort pipeline (3 dispatches)
    k_init_cur<<<2, 256, 0, stream>>>(bkcur);
    k_bucket1<<<B1B, 512, 0, stream>>>(row, col, ew, bkcur, tmp);
    k_bucket2<<<NBK, 256, 0, stream>>>(bkcur, tmp, sedge, begA, endA, dinv);

    // layer 1
    k_mm64<false><<<NN / 16, 256, 0, stream>>>(x, W1, A);
    k_agg<false><<<NN / 8, 256, 0, stream>>>(A, begA, endA, sedge, dinv, b1, B,
                                             nullptr, nullptr, nullptr);
    // layer 2 + fused head
    k_mm64<true><<<NN / 16, 256, 0, stream>>>(B, W2, A);
    k_agg<true><<<NN / 8, 256, 0, stream>>>(A, begA, endA, sedge, dinv, b2, B,
                                            Wout, bout, (float*)d_out);
}